// Round 9
// baseline (33.161 us; speedup 1.0000x reference)
//
#include <hip/hip_runtime.h>

#define NBLOCKS 8192
#define TPB 256
#define TPB_F 1024

typedef float f32x4 __attribute__((ext_vector_type(4)));

// Per-wave (64-lane) + per-block reduction of a double. Result valid in thread 0.
template <int NT>
__device__ __forceinline__ double block_reduce_d(double x) {
    #pragma unroll
    for (int off = 32; off > 0; off >>= 1)
        x += __shfl_down(x, off, 64);
    __shared__ double lds[NT / 64];
    const int lane = threadIdx.x & 63;
    const int wid  = threadIdx.x >> 6;
    if (lane == 0) lds[wid] = x;
    __syncthreads();
    if (wid == 0) {
        x = (lane < (NT / 64)) ? lds[lane] : 0.0;
        #pragma unroll
        for (int off = (NT / 128); off > 0; off >>= 1)
            x += __shfl_down(x, off, 64);
    }
    return x;
}

// Pair-cooperative row loss: lanes 2k,2k+1 hold halves of one row.
// Returns this lane's half-contribution (0.5x the row loss).
__device__ __forceinline__ float pair_loss(f32x4 v, int t, int half) {
    // local max + first-index argmax over my 4 (absolute level index)
    float m4 = v.x; int a4 = 0;
    if (v.y > m4) { m4 = v.y; a4 = 1; }
    if (v.z > m4) { m4 = v.z; a4 = 2; }
    if (v.w > m4) { m4 = v.w; a4 = 3; }
    a4 += half * 4;

    // combine with partner lane; ties go to the lower index (jnp.argmax)
    const float om = __shfl_xor(m4, 1, 64);
    const int   oa = __shfl_xor(a4, 1, 64);
    const float mlo = half ? om : m4;
    const float mhi = half ? m4 : om;
    const int   alo = half ? oa : a4;
    const int   ahi = half ? a4 : oa;
    const float m  = fmaxf(mlo, mhi);
    const int   am = (mhi > mlo) ? ahi : alo;

    // exp-sum (partner-combined)
    float s4 = __expf(v.x - m) + __expf(v.y - m)
             + __expf(v.z - m) + __expf(v.w - m);
    const float s = s4 + __shfl_xor(s4, 1, 64);

    // v[target]: exactly one lane of the pair contributes
    const int tb = t - half * 4;   // 0..3 if target in my half
    float vt4 = 0.f;
    vt4 = (tb == 0) ? v.x : vt4;
    vt4 = (tb == 1) ? v.y : vt4;
    vt4 = (tb == 2) ? v.z : vt4;
    vt4 = (tb == 3) ? v.w : vt4;
    const float vt = vt4 + __shfl_xor(vt4, 1, 64);

    const float ce = -(vt - m - __logf(s));
    int d = t - am; d = (d < 0) ? -d : d;
    return ce * (1.0f + (float)d) * 0.5f;
}

// Two-kernel structure (proven): fused last-block epilogue with device-scope
// fences costs ~70-120us on MI355X (cross-XCD L2 coherence) — do NOT fuse.
// R7/R8: unrolling the loop is neutral-to-negative — keep the simple stream.
__global__ __launch_bounds__(TPB) void hrl_partial(
    const float* __restrict__ pred,   // [batch, 8]
    const int*   __restrict__ tgt,    // [batch]
    double*      __restrict__ partial,// [NBLOCKS]
    int batch)
{
    const int lane = threadIdx.x & 63;
    const int half = lane & 1;        // which half-row I hold
    const int pair = lane >> 1;       // 0..31: row slot within the wave
    const int gwave  = (blockIdx.x * TPB + threadIdx.x) >> 6;
    const int nwaves = (NBLOCKS * TPB) >> 6;
    const int stride = nwaves * 32;   // rows per sweep

    const f32x4* __restrict__ pred4 = reinterpret_cast<const f32x4*>(pred);

    double acc = 0.0;
    for (int r = gwave * 32 + pair; r < batch; r += stride) {
        const f32x4 v = pred4[(size_t)r * 2 + half];
        acc += (double)pair_loss(v, tgt[r], half);
    }

    const double bsum = block_reduce_d<TPB>(acc);
    if (threadIdx.x == 0) partial[blockIdx.x] = bsum;  // overwrite: deterministic
}

__global__ __launch_bounds__(TPB_F) void hrl_final(
    const double* __restrict__ partial,
    float*        __restrict__ out,
    int nparts, double inv_batch)
{
    double s = 0.0;
    for (int i = threadIdx.x; i < nparts; i += TPB_F)
        s += partial[i];
    const double tot = block_reduce_d<TPB_F>(s);
    if (threadIdx.x == 0) out[0] = (float)(tot * inv_batch);
}

extern "C" void kernel_launch(void* const* d_in, const int* in_sizes, int n_in,
                              void* d_out, int out_size, void* d_ws, size_t ws_size,
                              hipStream_t stream) {
    const float* pred = (const float*)d_in[0];
    const int*   tgt  = (const int*)d_in[1];
    float*  out = (float*)d_out;
    double* ws  = (double*)d_ws;

    const int batch = in_sizes[0] / 8;  // predictions is [batch, 8]

    hrl_partial<<<NBLOCKS, TPB, 0, stream>>>(pred, tgt, ws, batch);
    hrl_final<<<1, TPB_F, 0, stream>>>(ws, out, NBLOCKS, 1.0 / (double)batch);
}

// Round 10
// 32.290 us; speedup vs baseline: 1.0270x; 1.0270x over previous
//
#include <hip/hip_runtime.h>

#define NBLOCKS 2048
#define TPB 256

typedef float f32x4 __attribute__((ext_vector_type(4)));

// Per-wave (64-lane) + per-block reduction of a double. Result valid in thread 0.
__device__ __forceinline__ double block_reduce_d(double x) {
    #pragma unroll
    for (int off = 32; off > 0; off >>= 1)
        x += __shfl_down(x, off, 64);
    __shared__ double lds[TPB / 64];
    const int lane = threadIdx.x & 63;
    const int wid  = threadIdx.x >> 6;
    if (lane == 0) lds[wid] = x;
    __syncthreads();
    if (wid == 0) {
        x = (lane < (TPB / 64)) ? lds[lane] : 0.0;
        #pragma unroll
        for (int off = (TPB / 128); off > 0; off >>= 1)
            x += __shfl_down(x, off, 64);
    }
    return x;
}

// Best-measured configuration (R7, 31.98us):
//  - lane-pair cooperation: lanes 2k,2k+1 co-own one row; each lane loads ONE
//    float4 -> 16B/lane contiguous across the wave (coalescing ideal).
//  - simple single-stream loop (unrolling x2/x4 tested neutral-to-negative 3x).
//  - two-kernel reduction (fused last-block epilogue costs 70-120us:
//    cross-XCD L2 coherence for __threadfence/atomic on MI355X).
//  - NBLOCKS=2048 (8/CU); 8192 tested worse.
//  - plain cached loads (nt-loads bypass L2/L3: 4x regression).
__global__ __launch_bounds__(TPB) void hrl_partial(
    const float* __restrict__ pred,   // [batch, 8]
    const int*   __restrict__ tgt,    // [batch]
    double*      __restrict__ partial,// [NBLOCKS]
    int batch)
{
    const int lane = threadIdx.x & 63;
    const int half = lane & 1;        // which half-row I hold (levels 4h..4h+3)
    const int pair = lane >> 1;       // 0..31: row slot within the wave
    const int gwave  = (blockIdx.x * TPB + threadIdx.x) >> 6;
    const int nwaves = (NBLOCKS * TPB) >> 6;

    const f32x4* __restrict__ pred4 = reinterpret_cast<const f32x4*>(pred);

    double acc = 0.0;
    for (int base = gwave * 32; base < batch; base += nwaves * 32) {
        const int r = base + pair;
        if (r < batch) {
            const f32x4 v = pred4[(size_t)r * 2 + half];
            const int   t = tgt[r];

            // local max + first-index argmax over my 4 (absolute index)
            float m4 = v.x; int a4 = 0;
            if (v.y > m4) { m4 = v.y; a4 = 1; }
            if (v.z > m4) { m4 = v.z; a4 = 2; }
            if (v.w > m4) { m4 = v.w; a4 = 3; }
            a4 += half * 4;

            // combine with partner lane; ties go to the lower index (jnp.argmax)
            const float om = __shfl_xor(m4, 1, 64);
            const int   oa = __shfl_xor(a4, 1, 64);
            const float mlo = half ? om : m4;
            const float mhi = half ? m4 : om;
            const int   alo = half ? oa : a4;
            const int   ahi = half ? a4 : oa;
            const float m  = fmaxf(mlo, mhi);
            const int   am = (mhi > mlo) ? ahi : alo;

            // exp-sum (partner-combined)
            float s4 = __expf(v.x - m) + __expf(v.y - m)
                     + __expf(v.z - m) + __expf(v.w - m);
            const float s = s4 + __shfl_xor(s4, 1, 64);

            // v[target]: exactly one lane of the pair contributes
            const int tb = t - half * 4;   // 0..3 if target in my half
            float vt4 = 0.f;
            vt4 = (tb == 0) ? v.x : vt4;
            vt4 = (tb == 1) ? v.y : vt4;
            vt4 = (tb == 2) ? v.z : vt4;
            vt4 = (tb == 3) ? v.w : vt4;
            const float vt = vt4 + __shfl_xor(vt4, 1, 64);

            const float ce = -(vt - m - __logf(s));
            int d = t - am; d = (d < 0) ? -d : d;
            // both lanes add half the loss (x0.5 is exact in double)
            acc += (double)(ce * (1.0f + (float)d)) * 0.5;
        }
    }

    const double bsum = block_reduce_d(acc);
    if (threadIdx.x == 0) partial[blockIdx.x] = bsum;  // overwrite: deterministic
}

__global__ __launch_bounds__(TPB) void hrl_final(
    const double* __restrict__ partial,
    float*        __restrict__ out,
    int nparts, double inv_batch)
{
    double s = 0.0;
    for (int i = threadIdx.x; i < nparts; i += TPB)
        s += partial[i];
    const double tot = block_reduce_d(s);
    if (threadIdx.x == 0) out[0] = (float)(tot * inv_batch);
}

extern "C" void kernel_launch(void* const* d_in, const int* in_sizes, int n_in,
                              void* d_out, int out_size, void* d_ws, size_t ws_size,
                              hipStream_t stream) {
    const float* pred = (const float*)d_in[0];
    const int*   tgt  = (const int*)d_in[1];
    float*  out = (float*)d_out;
    double* ws  = (double*)d_ws;

    const int batch = in_sizes[0] / 8;  // predictions is [batch, 8]

    hrl_partial<<<NBLOCKS, TPB, 0, stream>>>(pred, tgt, ws, batch);
    hrl_final<<<1, TPB, 0, stream>>>(ws, out, NBLOCKS, 1.0 / (double)batch);
}